// Round 18
// baseline (107.712 us; speedup 1.0000x reference)
//
#include <hip/hip_runtime.h>
#include <hip/hip_bf16.h>
#include <math.h>

// Problem constants (from reference)
constexpr int B_ = 8, Q_ = 900;
constexpr int S_ = 13294;
constexpr int BQ = 7200;     // B*Q
constexpr int BS = 106352;   // B*S
constexpr int NVB = 831;     // v-path blocks = ceil(BS/128)

typedef __bf16 bf16x8 __attribute__((ext_vector_type(8)));
typedef float  f32x4  __attribute__((ext_vector_type(4)));

#define WAITLGKM0 asm volatile("s_waitcnt lgkmcnt(0)" ::: "memory")
#define SCHEDB    __builtin_amdgcn_sched_barrier(0)
#define BAR       __builtin_amdgcn_s_barrier()
#define CFENCE    asm volatile("" ::: "memory")

__device__ __forceinline__ void load_lds16(const void* g, void* lds) {
    __builtin_amdgcn_global_load_lds(
        (const __attribute__((address_space(1))) void*)g,
        (__attribute__((address_space(3))) void*)lds, 16, 0, 0);
}

// Wcat[c][n] over the virtual [256][512] concat [wax | way | woff1(:256)].
__device__ __forceinline__ float wcat_f(const float* __restrict__ wax,
                                        const float* __restrict__ way,
                                        const float* __restrict__ woff1,
                                        int c, int n)
{
    if (n < 128) return wax[(size_t)c * 128 + n];
    if (n < 256) return way[(size_t)c * 128 + (n - 128)];
    return woff1[(size_t)c * 256 + (n - 256)];
}

// ---------------------------------------------------------------------------
// ONE prep launch (202 blocks):
//  bi 0..191  : transpose+cast w_v / w_o / w_off2 -> bf16 [N][K]  (R11 code)
//  bi 192..199: combine_w block b: in-LDS transpose of Wcat[:, b*64..+64)
//               (coalesced row reads), then wcomb = (Wq@Wcat)^T via MFMA.
//  bi 200..201: bcomb[n] (coalesced: lanes span n at fixed c)
// ---------------------------------------------------------------------------
__global__ __launch_bounds__(256)
void prep2(const float* __restrict__ wv, const float* __restrict__ wo,
           const float* __restrict__ woff2, const float* __restrict__ wq,
           const float* __restrict__ wax, const float* __restrict__ way,
           const float* __restrict__ woff1, const float* __restrict__ bq,
           const float* __restrict__ bax, const float* __restrict__ bay,
           const float* __restrict__ boff1,
           __bf16* __restrict__ tv, __bf16* __restrict__ to_,
           __bf16* __restrict__ toff2, __bf16* __restrict__ wcomb,
           float* __restrict__ bcomb)
{
    __shared__ float4 smem4[2112];   // 33792 B, reused per-branch
    const int bi  = blockIdx.x;
    const int tid = threadIdx.x;

    if (bi < 192) {
        float (*tile)[33] = (float(*)[33])smem4;
        const int wid = bi >> 6, t = bi & 63;
        const int k0 = (t & 7) * 32, n0 = (t >> 3) * 32;
        const int tx = tid & 31, ty = tid >> 5;
        const float* src; __bf16* dst;
        if      (wid == 0) { src = wv;    dst = tv;    }
        else if (wid == 1) { src = wo;    dst = to_;   }
        else               { src = woff2; dst = toff2; }
        #pragma unroll
        for (int i = 0; i < 4; ++i)
            tile[ty + 8 * i][tx] = src[(size_t)(k0 + ty + 8 * i) * 256 + n0 + tx];
        __syncthreads();
        #pragma unroll
        for (int i = 0; i < 4; ++i)
            dst[(size_t)(n0 + ty + 8 * i) * 256 + k0 + tx] = (__bf16)tile[tx][ty + 8 * i];
        return;
    }

    if (bi >= 200) {
        // bcomb: lanes span n at fixed c -> coalesced per source
        const int n = (bi - 200) * 256 + tid;
        float acc = (n < 128) ? bax[n] : (n < 256 ? bay[n - 128] : boff1[n - 256]);
        for (int c = 0; c < 256; ++c)
            acc += bq[c] * (float)(__bf16)wcat_f(wax, way, woff1, c, n);
        bcomb[n] = acc;
        return;
    }

    // ---- combine_w block b: n0 = b*64; 4 waves -> k0 = wave*64 ----
    __bf16 (*tileT)[264] = (__bf16(*)[264])smem4;   // [64 n][264 c], rows 528B (16B-aligned)
    const int b_  = bi - 192;
    const int n0  = b_ * 64;
    const int wave = tid >> 6, lane = tid & 63;
    const int k0  = wave * 64;
    const int l15 = lane & 15, l4 = lane >> 4;

    // in-LDS transpose: 16384 elems, lanes read Wcat rows (coalesced)
    #pragma unroll 4
    for (int it = 0; it < 64; ++it) {
        const int idx = it * 256 + tid;
        const int c = idx >> 6, j = idx & 63;
        tileT[j][c] = (__bf16)wcat_f(wax, way, woff1, c, n0 + j);
    }
    __syncthreads();

    f32x4 acc[4][4] = {};
    #pragma unroll
    for (int s = 0; s < 8; ++s) {
        const int c0 = s * 32 + l4 * 8;
        bf16x8 am[4], bm[4];
        #pragma unroll
        for (int mi = 0; mi < 4; ++mi)
            am[mi] = *(const bf16x8*)&tileT[mi * 16 + l15][c0];
        #pragma unroll
        for (int ni = 0; ni < 4; ++ni) {
            const float* wr_ = wq + (size_t)(k0 + ni * 16 + l15) * 256 + c0;
            const float4 f0 = ((const float4*)wr_)[0];
            const float4 f1 = ((const float4*)wr_)[1];
            bm[ni][0] = (__bf16)f0.x; bm[ni][1] = (__bf16)f0.y;
            bm[ni][2] = (__bf16)f0.z; bm[ni][3] = (__bf16)f0.w;
            bm[ni][4] = (__bf16)f1.x; bm[ni][5] = (__bf16)f1.y;
            bm[ni][6] = (__bf16)f1.z; bm[ni][7] = (__bf16)f1.w;
        }
        #pragma unroll
        for (int mi = 0; mi < 4; ++mi)
            #pragma unroll
            for (int ni = 0; ni < 4; ++ni)
                acc[mi][ni] = __builtin_amdgcn_mfma_f32_16x16x32_bf16(
                    am[mi], bm[ni], acc[mi][ni], 0, 0, 0);
    }
    #pragma unroll
    for (int mi = 0; mi < 4; ++mi)
        #pragma unroll
        for (int rr = 0; rr < 4; ++rr) {
            const int n = n0 + mi * 16 + l4 * 4 + rr;
            #pragma unroll
            for (int ni = 0; ni < 4; ++ni)
                wcomb[(size_t)n * 256 + k0 + ni * 16 + l15] = (__bf16)acc[mi][ni][rr];
        }
}

// ---------------------------------------------------------------------------
// Fused main GEMM (512 thr, 8 waves, 128x256 tile) — R11/R16/R17-VERIFIED.
//  blocks [0, NVB)      : v = x_in @ wt_v + b_v          -> bf16 v_bf
//  blocks [NVB, NVB+114): axyhid = query @ wcomb + bcomb -> f32
// ---------------------------------------------------------------------------
__global__ __launch_bounds__(512)
void main_fused(const float* __restrict__ x_in, const __bf16* __restrict__ wt_v,
                const float* __restrict__ b_v, __bf16* __restrict__ v_bf,
                const float* __restrict__ query, const __bf16* __restrict__ wcomb,
                const float* __restrict__ bcomb, const float* __restrict__ objs,
                const float* __restrict__ wex, float* __restrict__ axyhid)
{
    __shared__ float4 AsbV[2][512];    // 2 x 8KB
    __shared__ float4 BsbV[3][1024];   // 3 x 16KB
    char* const Asb_b = (char*)AsbV;
    char* const Bsb_b = (char*)BsbV;

    const int bid  = blockIdx.x;
    const bool isV = (bid < NVB);
    const int qb   = bid - NVB;
    const int colhalf = isV ? 0 : (qb & 1);

    const float*  A    = isV ? x_in : query;
    const __bf16* Wt   = isV ? wt_v : (wcomb + (size_t)colhalf * 256 * 256);
    const float*  bias = isV ? b_v  : (bcomb + colhalf * 256);
    const int     M    = isV ? BS   : BQ;
    const int     row0 = isV ? bid * 128 : (qb >> 1) * 128;

    const int tid  = threadIdx.x;
    const int wave = tid >> 6, lane = tid & 63;
    const int wr = wave >> 2, wc = wave & 3;
    const int l15 = lane & 15, l4 = lane >> 4;

    const int st_row = tid >> 2, st_kq = tid & 3;
    const int gr_cl  = min(row0 + st_row, M - 1);
    const float* Abase = A + (size_t)gr_cl * 256 + st_kq * 8;
    const int a_wo = st_row * 64 + ((st_kq ^ ((st_row >> 1) & 3)) * 16);

    int a_off[4], b_off[4];
    #pragma unroll
    for (int mi = 0; mi < 4; ++mi) {
        const int r = wr * 64 + mi * 16 + l15;
        a_off[mi] = r * 64 + (l4 ^ ((r >> 1) & 3)) * 16;
    }
    #pragma unroll
    for (int ni = 0; ni < 4; ++ni) {
        const int c = wc * 64 + ni * 16 + l15;
        b_off[ni] = c * 64 + (l4 ^ ((c >> 1) & 3)) * 16;
    }

    const __bf16* bsrc[2];
    #pragma unroll
    for (int i = 0; i < 2; ++i) {
        const int c   = (wave * 2 + i) * 64 + lane;
        const int col = c >> 2, kcp = c & 3;
        const int kc  = kcp ^ ((col >> 1) & 3);
        bsrc[i] = Wt + (size_t)col * 256 + kc * 8;
    }

    auto issueB = [&](int kt, int bbuf) {
        #pragma unroll
        for (int i = 0; i < 2; ++i)
            load_lds16(bsrc[i] + kt * 32, Bsb_b + bbuf * 16384 + (wave * 2 + i) * 1024);
    };
    auto loadA = [&](int kt, float4* g) {
        const float* ga = Abase + kt * 32;
        g[0] = ((const float4*)ga)[0];
        g[1] = ((const float4*)ga)[1];
    };
    auto writeA = [&](int abuf, const float4* g) {
        bf16x8 c0;
        c0[0] = (__bf16)g[0].x; c0[1] = (__bf16)g[0].y; c0[2] = (__bf16)g[0].z; c0[3] = (__bf16)g[0].w;
        c0[4] = (__bf16)g[1].x; c0[5] = (__bf16)g[1].y; c0[6] = (__bf16)g[1].z; c0[7] = (__bf16)g[1].w;
        *(bf16x8*)(Asb_b + abuf * 8192 + a_wo) = c0;
    };

    f32x4 acc[4][4] = {};
    float4 g[2][2];

    issueB(0, 0);
    loadA(0, g[0]);
    issueB(1, 1);
    loadA(1, g[1]);
    writeA(0, g[0]);
    WAITLGKM0; BAR; CFENCE; SCHEDB;

    #pragma unroll
    for (int u = 0; u < 8; ++u) {
        if (u + 2 <= 7) {
            loadA(u + 2, g[u & 1]);
            issueB(u + 2, (u + 2) % 3);
        }

        if (u < 6)       { asm volatile("s_waitcnt vmcnt(8)" ::: "memory"); }
        else if (u == 6) { asm volatile("s_waitcnt vmcnt(4)" ::: "memory"); }
        else             { asm volatile("s_waitcnt vmcnt(0)" ::: "memory"); }
        SCHEDB;

        const char* Ab = Asb_b + (u & 1) * 8192;
        const char* Bb = Bsb_b + (u % 3) * 16384;
        bf16x8 a[4], b[4];
        #pragma unroll
        for (int mi = 0; mi < 4; ++mi) a[mi] = *(const bf16x8*)(Ab + a_off[mi]);
        #pragma unroll
        for (int ni = 0; ni < 4; ++ni) b[ni] = *(const bf16x8*)(Bb + b_off[ni]);

        #pragma unroll
        for (int mi = 0; mi < 4; ++mi)
            #pragma unroll
            for (int ni = 0; ni < 4; ++ni)
                acc[mi][ni] = __builtin_amdgcn_mfma_f32_16x16x32_bf16(
                    a[mi], b[ni], acc[mi][ni], 0, 0, 0);

        if (u + 1 <= 7) {
            writeA((u + 1) & 1, g[(u + 1) & 1]);
            WAITLGKM0; BAR; CFENCE; SCHEDB;
        }
    }

    float bb[4];
    #pragma unroll
    for (int ni = 0; ni < 4; ++ni) bb[ni] = bias[wc * 64 + ni * 16 + l15];

    if (isV) {
        #pragma unroll
        for (int mi = 0; mi < 4; ++mi)
            #pragma unroll
            for (int rr = 0; rr < 4; ++rr) {
                const int row = row0 + wr * 64 + mi * 16 + l4 * 4 + rr;
                if (row >= M) continue;
                #pragma unroll
                for (int ni = 0; ni < 4; ++ni)
                    v_bf[(size_t)row * 256 + wc * 64 + ni * 16 + l15] =
                        (__bf16)(acc[mi][ni][rr] + bb[ni]);
            }
    } else {
        float we0[4], we1[4];
        #pragma unroll
        for (int ni = 0; ni < 4; ++ni) {
            const int c = wc * 64 + ni * 16 + l15;
            we0[ni] = colhalf ? wex[c]       : 0.f;
            we1[ni] = colhalf ? wex[256 + c] : 0.f;
        }
        #pragma unroll
        for (int mi = 0; mi < 4; ++mi)
            #pragma unroll
            for (int rr = 0; rr < 4; ++rr) {
                const int row = row0 + wr * 64 + mi * 16 + l4 * 4 + rr;
                if (row >= M) continue;
                const float e0 = objs[(size_t)row * 2];
                const float e1 = objs[(size_t)row * 2 + 1];
                #pragma unroll
                for (int ni = 0; ni < 4; ++ni) {
                    const int c = wc * 64 + ni * 16 + l15;
                    float v = acc[mi][ni][rr] + bb[ni];
                    if (colhalf) {
                        v += e0 * we0[ni] + e1 * we1[ni];
                        v = fmaxf(v, 0.f);
                    }
                    axyhid[(size_t)row * 512 + colhalf * 256 + c] = v;
                }
            }
    }
}

// ---------------------------------------------------------------------------
// Deep-pipelined bf16 MFMA GEMM, 4-wave 128x128 (R11/R16/R17-verified)
// ---------------------------------------------------------------------------
template<bool OUTBF16>
__global__ __launch_bounds__(256)
void gemm_dp(const float* __restrict__ A, const __bf16* __restrict__ Wt,
             const float* __restrict__ bias, void* __restrict__ outp,
             int M, int N, int LDA)
{
    __shared__ float4 AsbV[2][512];
    __shared__ float4 BsbV[3][512];
    char* const Asb_b = (char*)AsbV;
    char* const Bsb_b = (char*)BsbV;

    const int tid  = threadIdx.x;
    const int wave = tid >> 6, lane = tid & 63;
    const int wr = wave >> 1, wc = wave & 1;
    const int row0 = blockIdx.y * 128, col0 = blockIdx.x * 128;
    const int l15 = lane & 15, l4 = lane >> 4;

    const int st_row = tid >> 1, st_kh = tid & 1;
    const int gr_cl  = min(row0 + st_row, M - 1);
    const float* Abase = A + (size_t)gr_cl * LDA + st_kh * 16;
    const int asw   = (st_row >> 1) & 3;
    const int a_wo0 = st_row * 64 + ((st_kh * 2)     ^ asw) * 16;
    const int a_wo1 = st_row * 64 + ((st_kh * 2 + 1) ^ asw) * 16;

    int a_off[4], b_off[4];
    #pragma unroll
    for (int mi = 0; mi < 4; ++mi) {
        const int r   = wr * 64 + mi * 16 + l15;
        a_off[mi] = r * 64 + (l4 ^ ((r >> 1) & 3)) * 16;
    }
    #pragma unroll
    for (int ni = 0; ni < 4; ++ni) {
        const int c   = wc * 64 + ni * 16 + l15;
        b_off[ni] = c * 64 + (l4 ^ ((c >> 1) & 3)) * 16;
    }

    const __bf16* bsrc[2];
    #pragma unroll
    for (int i = 0; i < 2; ++i) {
        const int c   = (wave * 2 + i) * 64 + lane;
        const int col = c >> 2, kcp = c & 3;
        const int kc  = kcp ^ ((col >> 1) & 3);
        bsrc[i] = Wt + (size_t)(col0 + col) * 256 + kc * 8;
    }

    auto issueB = [&](int kt, int bbuf) {
        #pragma unroll
        for (int i = 0; i < 2; ++i)
            load_lds16(bsrc[i] + kt * 32, Bsb_b + bbuf * 8192 + (wave * 2 + i) * 1024);
    };
    auto loadA = [&](int kt, float4* g) {
        const float* ga = Abase + kt * 32;
        g[0] = ((const float4*)ga)[0];
        g[1] = ((const float4*)ga)[1];
        g[2] = ((const float4*)ga)[2];
        g[3] = ((const float4*)ga)[3];
    };
    auto writeA = [&](int abuf, const float4* g) {
        bf16x8 c0, c1;
        c0[0] = (__bf16)g[0].x; c0[1] = (__bf16)g[0].y; c0[2] = (__bf16)g[0].z; c0[3] = (__bf16)g[0].w;
        c0[4] = (__bf16)g[1].x; c0[5] = (__bf16)g[1].y; c0[6] = (__bf16)g[1].z; c0[7] = (__bf16)g[1].w;
        c1[0] = (__bf16)g[2].x; c1[1] = (__bf16)g[2].y; c1[2] = (__bf16)g[2].z; c1[3] = (__bf16)g[2].w;
        c1[4] = (__bf16)g[3].x; c1[5] = (__bf16)g[3].y; c1[6] = (__bf16)g[3].z; c1[7] = (__bf16)g[3].w;
        *(bf16x8*)(Asb_b + abuf * 8192 + a_wo0) = c0;
        *(bf16x8*)(Asb_b + abuf * 8192 + a_wo1) = c1;
    };

    f32x4 acc[4][4] = {};
    float4 g[2][4];

    issueB(0, 0);
    loadA(0, g[0]);
    issueB(1, 1);
    loadA(1, g[1]);
    writeA(0, g[0]);
    WAITLGKM0; BAR; CFENCE; SCHEDB;

    #pragma unroll
    for (int u = 0; u < 8; ++u) {
        if (u + 2 <= 7) {
            loadA(u + 2, g[u & 1]);
            issueB(u + 2, (u + 2) % 3);
        }

        if (u < 6)       { asm volatile("s_waitcnt vmcnt(12)" ::: "memory"); }
        else if (u == 6) { asm volatile("s_waitcnt vmcnt(6)" ::: "memory"); }
        else             { asm volatile("s_waitcnt vmcnt(0)" ::: "memory"); }
        SCHEDB;

        const char* Ab = Asb_b + (u & 1) * 8192;
        const char* Bb = Bsb_b + (u % 3) * 8192;
        bf16x8 a[4], b[4];
        #pragma unroll
        for (int mi = 0; mi < 4; ++mi) a[mi] = *(const bf16x8*)(Ab + a_off[mi]);
        #pragma unroll
        for (int ni = 0; ni < 4; ++ni) b[ni] = *(const bf16x8*)(Bb + b_off[ni]);

        #pragma unroll
        for (int mi = 0; mi < 4; ++mi)
            #pragma unroll
            for (int ni = 0; ni < 4; ++ni)
                acc[mi][ni] = __builtin_amdgcn_mfma_f32_16x16x32_bf16(
                    a[mi], b[ni], acc[mi][ni], 0, 0, 0);

        if (u + 1 <= 7) {
            writeA((u + 1) & 1, g[(u + 1) & 1]);
            WAITLGKM0; BAR; CFENCE; SCHEDB;
        }
    }

    float bb[4];
    #pragma unroll
    for (int ni = 0; ni < 4; ++ni) bb[ni] = bias[col0 + wc * 64 + ni * 16 + l15];
    #pragma unroll
    for (int mi = 0; mi < 4; ++mi) {
        #pragma unroll
        for (int rr = 0; rr < 4; ++rr) {
            const int row = row0 + wr * 64 + mi * 16 + l4 * 4 + rr;
            if (row >= M) continue;
            #pragma unroll
            for (int ni = 0; ni < 4; ++ni) {
                const float v = acc[mi][ni][rr] + bb[ni];
                const int colb = col0 + wc * 64 + ni * 16 + l15;
                if (OUTBF16) ((__bf16*)outp)[(size_t)row * N + colb] = (__bf16)v;
                else         ((float*)outp)[(size_t)row * N + colb]  = v;
            }
        }
    }
}

// ---------------------------------------------------------------------------
// Fused: softmax (spec cancels) + locations + VECTORIZED bilinear sampling.
// XCD-aware bq swizzle (T1, R17-verified): bq = (bid&7)*900 + (bid>>3).
// ---------------------------------------------------------------------------
__global__ __launch_bounds__(256)
void attn_sample_kernel(const float* __restrict__ axyhid,
                        const float* __restrict__ refp, const float* __restrict__ objs,
                        const float* __restrict__ off, const __bf16* __restrict__ v,
                        float* __restrict__ agg)
{
    const int bid = blockIdx.x;
    const int bq  = (bid & 7) * 900 + (bid >> 3);
    const int b   = bid & 7;
    const int tid = threadIdx.x;

    __shared__ float sm[128];
    __shared__ float sa[128];
    __shared__ float sl[256];

    if (tid < 128)
        sm[tid] = axyhid[(size_t)bq * 512 + tid] * axyhid[(size_t)bq * 512 + 128 + tid];
    __syncthreads();

    if (tid < 128) {
        const int hh = tid >> 4;
        float mx = -1e30f;
        #pragma unroll
        for (int i = 0; i < 16; ++i) mx = fmaxf(mx, sm[hh * 16 + i]);
        float s = 0.f;
        #pragma unroll
        for (int i = 0; i < 16; ++i) s += __expf(sm[hh * 16 + i] - mx);
        sa[tid] = __expf(sm[tid] - mx) / s;

        const int l = (tid >> 2) & 3;
        const float os0 = objs[(size_t)bq * 2], os1 = objs[(size_t)bq * 2 + 1];
        const float r0 = refp[((size_t)bq * 4 + l) * 2];
        const float r1 = refp[((size_t)bq * 4 + l) * 2 + 1];
        const float o0 = off[(size_t)bq * 256 + tid * 2]     * os0;
        const float o1 = off[(size_t)bq * 256 + tid * 2 + 1] * os1;
        sl[tid * 2]     = fminf(fmaxf(r0 + o0, 0.f), 1.f);
        sl[tid * 2 + 1] = fminf(fmaxf(r1 + o1, 0.f), 1.f);
    }
    __syncthreads();

    const int h = tid >> 5, lane32 = tid & 31;
    const int sp = lane32 >> 2, cq = lane32 & 3;
    const int chbase = h * 32 + cq * 8;
    const __bf16* vb = v + (size_t)b * S_ * 256;

    float acc8[8] = {};

    #pragma unroll
    for (int gidx = 0; gidx < 2; ++gidx) {
        const int lp  = gidx * 8 + sp;
        const int li  = h * 16 + lp;
        const int lvl = lp >> 2;
        const int Wl = (lvl == 0) ? 100 : (lvl == 1) ? 50 : (lvl == 2) ? 25 : 13;
        const int Hl = Wl;
        const int st = (lvl == 0) ? 0 : (lvl == 1) ? 10000 : (lvl == 2) ? 12500 : 13125;

        const float a  = sa[li];
        const float lx = sl[li * 2], ly = sl[li * 2 + 1];
        const float x = lx * (float)Wl - 0.5f;
        const float y = ly * (float)Hl - 0.5f;
        const float x0f = floorf(x), y0f = floorf(y);
        const float fx = x - x0f, fy = y - y0f;
        const int x0 = (int)x0f, y0 = (int)y0f;

        #pragma unroll
        for (int c = 0; c < 4; ++c) {
            const int dx = c & 1, dy = c >> 1;
            const int xi = x0 + dx, yi = y0 + dy;
            const float wgt = (dx ? fx : 1.f - fx) * (dy ? fy : 1.f - fy);
            const bool valid = (xi >= 0) & (xi < Wl) & (yi >= 0) & (yi < Hl);
            const int idx = min(max(yi, 0), Hl - 1) * Wl + min(max(xi, 0), Wl - 1);
            const float wa = valid ? a * wgt : 0.f;
            const bf16x8 gv = *(const bf16x8*)(vb + (size_t)(st + idx) * 256 + chbase);
            #pragma unroll
            for (int j = 0; j < 8; ++j) acc8[j] += wa * (float)gv[j];
        }
    }

    #pragma unroll
    for (int m = 4; m <= 16; m <<= 1)
        #pragma unroll
        for (int j = 0; j < 8; ++j)
            acc8[j] += __shfl_xor(acc8[j], m);

    if (sp == 0) {
        #pragma unroll
        for (int j = 0; j < 8; ++j)
            agg[(size_t)bq * 256 + chbase + j] = acc8[j];
    }
}

// ---------------------------------------------------------------------------
extern "C" void kernel_launch(void* const* d_in, const int* in_sizes, int n_in,
                              void* d_out, int out_size, void* d_ws, size_t ws_size,
                              hipStream_t stream)
{
    const float* query = (const float*)d_in[0];
    const float* refp  = (const float*)d_in[1];
    const float* x_in  = (const float*)d_in[2];
    const float* objs  = (const float*)d_in[3];
    const float* w_q    = (const float*)d_in[6];
    const float* b_q    = (const float*)d_in[7];
    const float* w_v    = (const float*)d_in[8];
    const float* b_v    = (const float*)d_in[9];
    const float* w_o    = (const float*)d_in[10];
    const float* b_o    = (const float*)d_in[11];
    const float* w_off1 = (const float*)d_in[12];
    const float* b_off1 = (const float*)d_in[13];
    const float* w_off2 = (const float*)d_in[14];
    const float* b_off2 = (const float*)d_in[15];
    const float* w_ax   = (const float*)d_in[16];
    const float* b_ax   = (const float*)d_in[17];
    const float* w_ay   = (const float*)d_in[18];
    const float* b_ay   = (const float*)d_in[19];

    float* ws = (float*)d_ws;
    float* axyhid_ws = ws;                               // BQ*512 f32
    float* off_ws    = axyhid_ws + (size_t)BQ * 512;     // BQ*256 f32
    float* agg_ws    = off_ws    + (size_t)BQ * 256;     // BQ*256 f32
    float* bcomb_ws  = agg_ws    + (size_t)BQ * 256;     // 512 f32
    __bf16* v_bf    = (__bf16*)(bcomb_ws + 512);         // BS*256 bf16
    __bf16* wt_v    = v_bf    + (size_t)BS * 256;
    __bf16* wt_o    = wt_v    + 256 * 256;
    __bf16* wt_off2 = wt_o    + 256 * 256;
    __bf16* wcomb   = wt_off2 + 256 * 256;               // 512*256

    const dim3 blk(256);

    // ONE prep launch: transposes + self-contained weight/bias combine
    prep2<<<202, blk, 0, stream>>>(w_v, w_o, w_off2, w_q, w_ax, w_ay, w_off1,
                                   b_q, b_ax, b_ay, b_off1,
                                   wt_v, wt_o, wt_off2, wcomb, bcomb_ws);

    // fused: v-GEMM (831 blocks) + axyhid GEMM (114 blocks)
    main_fused<<<NVB + 114, dim3(512), 0, stream>>>(
        x_in, wt_v, b_v, v_bf,
        query, wcomb, bcomb_ws, objs, w_off1 + 256 * 256, axyhid_ws);

    // offsets = hid @ w_off2 + b_off2 -> f32
    gemm_dp<false><<<dim3(2, (BQ + 127) / 128), blk, 0, stream>>>(
        axyhid_ws + 256, wt_off2, b_off2, off_ws, BQ, 256, 512);

    // fused softmax/locs/sampling (vectorized gathers + XCD swizzle)
    attn_sample_kernel<<<BQ, blk, 0, stream>>>(axyhid_ws, refp, objs, off_ws,
                                               v_bf, agg_ws);

    // out = agg @ w_o + b_o -> f32
    gemm_dp<false><<<dim3(2, (BQ + 127) / 128), blk, 0, stream>>>(
        agg_ws, wt_o, b_o, (float*)d_out, BQ, 256, 256);
}

// Round 19
// 99.419 us; speedup vs baseline: 1.0834x; 1.0834x over previous
//
#include <hip/hip_runtime.h>
#include <hip/hip_bf16.h>
#include <math.h>

// Problem constants (from reference)
constexpr int B_ = 8, Q_ = 900;
constexpr int S_ = 13294;
constexpr int BQ = 7200;     // B*Q
constexpr int BS = 106352;   // B*S
constexpr int NVB = 831;     // v-path blocks = ceil(BS/128)

typedef __bf16 bf16x8 __attribute__((ext_vector_type(8)));
typedef float  f32x4  __attribute__((ext_vector_type(4)));

#define WAITLGKM0 asm volatile("s_waitcnt lgkmcnt(0)" ::: "memory")
#define SCHEDB    __builtin_amdgcn_sched_barrier(0)
#define BAR       __builtin_amdgcn_s_barrier()
#define CFENCE    asm volatile("" ::: "memory")

__device__ __forceinline__ void load_lds16(const void* g, void* lds) {
    __builtin_amdgcn_global_load_lds(
        (const __attribute__((address_space(1))) void*)g,
        (__attribute__((address_space(3))) void*)lds, 16, 0, 0);
}

// ---------------------------------------------------------------------------
// Fused transpose+cast of weights into bf16 [N][K=256] layouts. (R11-verified)
// bi 0..63: w_v | 64..127: w_o | 128..191: w_off2 | 192..319: tcat[512][256]
// ---------------------------------------------------------------------------
__global__ __launch_bounds__(256)
void transpose_all(const float* __restrict__ wv, const float* __restrict__ wo,
                   const float* __restrict__ woff1, const float* __restrict__ woff2,
                   const float* __restrict__ wax, const float* __restrict__ way,
                   __bf16* __restrict__ tv, __bf16* __restrict__ to_,
                   __bf16* __restrict__ toff2, __bf16* __restrict__ tcat)
{
    const int bi = blockIdx.x;
    __shared__ float tile[32][33];
    const int tx = threadIdx.x & 31, ty = threadIdx.x >> 5;

    const float* src; __bf16* dst; int k0, n0, scol, sN = 256;
    if (bi < 192) {
        const int wid = bi >> 6, t = bi & 63;
        k0 = (t & 7) * 32; n0 = (t >> 3) * 32; scol = n0;
        if      (wid == 0) { src = wv;    dst = tv;    }
        else if (wid == 1) { src = wo;    dst = to_;   }
        else               { src = woff2; dst = toff2; }
    } else {
        const int t = bi - 192;
        k0 = (t & 7) * 32; n0 = (t >> 3) * 32;
        dst = tcat;
        if      (n0 < 128) { src = wax;   scol = n0;       sN = 128; }
        else if (n0 < 256) { src = way;   scol = n0 - 128; sN = 128; }
        else               { src = woff1; scol = n0 - 256; sN = 256; }
    }

    #pragma unroll
    for (int i = 0; i < 4; ++i)
        tile[ty + 8 * i][tx] = src[(size_t)(k0 + ty + 8 * i) * sN + scol + tx];
    __syncthreads();
    #pragma unroll
    for (int i = 0; i < 4; ++i)
        dst[(size_t)(n0 + ty + 8 * i) * 256 + k0 + tx] = (__bf16)tile[tx][ty + 8 * i];
}

// ---------------------------------------------------------------------------
// Merged combine (R11-verified): blocks 0..7 -> wcomb; 8..9 -> bcomb
// ---------------------------------------------------------------------------
__global__ __launch_bounds__(256)
void combine2(const __bf16* __restrict__ tcat, const float* __restrict__ wq,
              const float* __restrict__ bq, const float* __restrict__ bax,
              const float* __restrict__ bay, const float* __restrict__ boff1,
              __bf16* __restrict__ wcomb, float* __restrict__ bcomb)
{
    const int bi = blockIdx.x;
    if (bi >= 8) {
        const int n = (bi - 8) * 256 + threadIdx.x;
        float acc = (n < 128) ? bax[n] : (n < 256 ? bay[n - 128] : boff1[n - 256]);
        const __bf16* row = tcat + (size_t)n * 256;
        #pragma unroll 4
        for (int c8 = 0; c8 < 32; ++c8) {
            const bf16x8 rv = *(const bf16x8*)(row + c8 * 8);
            #pragma unroll
            for (int j = 0; j < 8; ++j) acc += bq[c8 * 8 + j] * (float)rv[j];
        }
        bcomb[n] = acc;
        return;
    }

    const int wid  = (bi << 2) + (threadIdx.x >> 6);
    const int lane = threadIdx.x & 63;
    const int n0 = (wid >> 2) * 64, k0 = (wid & 3) * 64;
    const int l15 = lane & 15, l4 = lane >> 4;

    f32x4 acc[4][4] = {};
    #pragma unroll
    for (int s = 0; s < 8; ++s) {
        const int c0 = s * 32 + l4 * 8;
        bf16x8 am[4], bm[4];
        #pragma unroll
        for (int mi = 0; mi < 4; ++mi)
            am[mi] = *(const bf16x8*)(tcat + (size_t)(n0 + mi * 16 + l15) * 256 + c0);
        #pragma unroll
        for (int ni = 0; ni < 4; ++ni) {
            const float* wr_ = wq + (size_t)(k0 + ni * 16 + l15) * 256 + c0;
            const float4 f0 = ((const float4*)wr_)[0];
            const float4 f1 = ((const float4*)wr_)[1];
            bm[ni][0] = (__bf16)f0.x; bm[ni][1] = (__bf16)f0.y;
            bm[ni][2] = (__bf16)f0.z; bm[ni][3] = (__bf16)f0.w;
            bm[ni][4] = (__bf16)f1.x; bm[ni][5] = (__bf16)f1.y;
            bm[ni][6] = (__bf16)f1.z; bm[ni][7] = (__bf16)f1.w;
        }
        #pragma unroll
        for (int mi = 0; mi < 4; ++mi)
            #pragma unroll
            for (int ni = 0; ni < 4; ++ni)
                acc[mi][ni] = __builtin_amdgcn_mfma_f32_16x16x32_bf16(
                    am[mi], bm[ni], acc[mi][ni], 0, 0, 0);
    }
    #pragma unroll
    for (int mi = 0; mi < 4; ++mi)
        #pragma unroll
        for (int rr = 0; rr < 4; ++rr) {
            const int n = n0 + mi * 16 + l4 * 4 + rr;
            #pragma unroll
            for (int ni = 0; ni < 4; ++ni)
                wcomb[(size_t)n * 256 + k0 + ni * 16 + l15] = (__bf16)acc[mi][ni][rr];
        }
}

// ---------------------------------------------------------------------------
// Fused main GEMM (512 thr, 8 waves, 128x256 tile) — R11/R16/R17-VERIFIED.
//  blocks [0, NVB)      : v = x_in @ wt_v + b_v          -> bf16 v_bf
//  blocks [NVB, NVB+114): axyhid = query @ wcomb + bcomb -> f32
// ---------------------------------------------------------------------------
__global__ __launch_bounds__(512)
void main_fused(const float* __restrict__ x_in, const __bf16* __restrict__ wt_v,
                const float* __restrict__ b_v, __bf16* __restrict__ v_bf,
                const float* __restrict__ query, const __bf16* __restrict__ wcomb,
                const float* __restrict__ bcomb, const float* __restrict__ objs,
                const float* __restrict__ wex, float* __restrict__ axyhid)
{
    __shared__ float4 AsbV[2][512];    // 2 x 8KB
    __shared__ float4 BsbV[3][1024];   // 3 x 16KB
    char* const Asb_b = (char*)AsbV;
    char* const Bsb_b = (char*)BsbV;

    const int bid  = blockIdx.x;
    const bool isV = (bid < NVB);
    const int qb   = bid - NVB;
    const int colhalf = isV ? 0 : (qb & 1);

    const float*  A    = isV ? x_in : query;
    const __bf16* Wt   = isV ? wt_v : (wcomb + (size_t)colhalf * 256 * 256);
    const float*  bias = isV ? b_v  : (bcomb + colhalf * 256);
    const int     M    = isV ? BS   : BQ;
    const int     row0 = isV ? bid * 128 : (qb >> 1) * 128;

    const int tid  = threadIdx.x;
    const int wave = tid >> 6, lane = tid & 63;
    const int wr = wave >> 2, wc = wave & 3;
    const int l15 = lane & 15, l4 = lane >> 4;

    const int st_row = tid >> 2, st_kq = tid & 3;
    const int gr_cl  = min(row0 + st_row, M - 1);
    const float* Abase = A + (size_t)gr_cl * 256 + st_kq * 8;
    const int a_wo = st_row * 64 + ((st_kq ^ ((st_row >> 1) & 3)) * 16);

    int a_off[4], b_off[4];
    #pragma unroll
    for (int mi = 0; mi < 4; ++mi) {
        const int r = wr * 64 + mi * 16 + l15;
        a_off[mi] = r * 64 + (l4 ^ ((r >> 1) & 3)) * 16;
    }
    #pragma unroll
    for (int ni = 0; ni < 4; ++ni) {
        const int c = wc * 64 + ni * 16 + l15;
        b_off[ni] = c * 64 + (l4 ^ ((c >> 1) & 3)) * 16;
    }

    const __bf16* bsrc[2];
    #pragma unroll
    for (int i = 0; i < 2; ++i) {
        const int c   = (wave * 2 + i) * 64 + lane;
        const int col = c >> 2, kcp = c & 3;
        const int kc  = kcp ^ ((col >> 1) & 3);
        bsrc[i] = Wt + (size_t)col * 256 + kc * 8;
    }

    auto issueB = [&](int kt, int bbuf) {
        #pragma unroll
        for (int i = 0; i < 2; ++i)
            load_lds16(bsrc[i] + kt * 32, Bsb_b + bbuf * 16384 + (wave * 2 + i) * 1024);
    };
    auto loadA = [&](int kt, float4* g) {
        const float* ga = Abase + kt * 32;
        g[0] = ((const float4*)ga)[0];
        g[1] = ((const float4*)ga)[1];
    };
    auto writeA = [&](int abuf, const float4* g) {
        bf16x8 c0;
        c0[0] = (__bf16)g[0].x; c0[1] = (__bf16)g[0].y; c0[2] = (__bf16)g[0].z; c0[3] = (__bf16)g[0].w;
        c0[4] = (__bf16)g[1].x; c0[5] = (__bf16)g[1].y; c0[6] = (__bf16)g[1].z; c0[7] = (__bf16)g[1].w;
        *(bf16x8*)(Asb_b + abuf * 8192 + a_wo) = c0;
    };

    f32x4 acc[4][4] = {};
    float4 g[2][2];

    issueB(0, 0);
    loadA(0, g[0]);
    issueB(1, 1);
    loadA(1, g[1]);
    writeA(0, g[0]);
    WAITLGKM0; BAR; CFENCE; SCHEDB;

    #pragma unroll
    for (int u = 0; u < 8; ++u) {
        if (u + 2 <= 7) {
            loadA(u + 2, g[u & 1]);
            issueB(u + 2, (u + 2) % 3);
        }

        // counted wait: guarantee B(u) glds landed (FIFO; normally already met)
        if (u < 6)       { asm volatile("s_waitcnt vmcnt(8)" ::: "memory"); }
        else if (u == 6) { asm volatile("s_waitcnt vmcnt(4)" ::: "memory"); }
        else             { asm volatile("s_waitcnt vmcnt(0)" ::: "memory"); }
        SCHEDB;

        const char* Ab = Asb_b + (u & 1) * 8192;
        const char* Bb = Bsb_b + (u % 3) * 16384;
        bf16x8 a[4], b[4];
        #pragma unroll
        for (int mi = 0; mi < 4; ++mi) a[mi] = *(const bf16x8*)(Ab + a_off[mi]);
        #pragma unroll
        for (int ni = 0; ni < 4; ++ni) b[ni] = *(const bf16x8*)(Bb + b_off[ni]);

        #pragma unroll
        for (int mi = 0; mi < 4; ++mi)
            #pragma unroll
            for (int ni = 0; ni < 4; ++ni)
                acc[mi][ni] = __builtin_amdgcn_mfma_f32_16x16x32_bf16(
                    a[mi], b[ni], acc[mi][ni], 0, 0, 0);

        if (u + 1 <= 7) {
            writeA((u + 1) & 1, g[(u + 1) & 1]);
            WAITLGKM0; BAR; CFENCE; SCHEDB;
        }
    }

    float bb[4];
    #pragma unroll
    for (int ni = 0; ni < 4; ++ni) bb[ni] = bias[wc * 64 + ni * 16 + l15];

    if (isV) {
        #pragma unroll
        for (int mi = 0; mi < 4; ++mi)
            #pragma unroll
            for (int rr = 0; rr < 4; ++rr) {
                const int row = row0 + wr * 64 + mi * 16 + l4 * 4 + rr;
                if (row >= M) continue;
                #pragma unroll
                for (int ni = 0; ni < 4; ++ni)
                    v_bf[(size_t)row * 256 + wc * 64 + ni * 16 + l15] =
                        (__bf16)(acc[mi][ni][rr] + bb[ni]);
            }
    } else {
        float we0[4], we1[4];
        #pragma unroll
        for (int ni = 0; ni < 4; ++ni) {
            const int c = wc * 64 + ni * 16 + l15;
            we0[ni] = colhalf ? wex[c]       : 0.f;
            we1[ni] = colhalf ? wex[256 + c] : 0.f;
        }
        #pragma unroll
        for (int mi = 0; mi < 4; ++mi)
            #pragma unroll
            for (int rr = 0; rr < 4; ++rr) {
                const int row = row0 + wr * 64 + mi * 16 + l4 * 4 + rr;
                if (row >= M) continue;
                const float e0 = objs[(size_t)row * 2];
                const float e1 = objs[(size_t)row * 2 + 1];
                #pragma unroll
                for (int ni = 0; ni < 4; ++ni) {
                    const int c = wc * 64 + ni * 16 + l15;
                    float v = acc[mi][ni][rr] + bb[ni];
                    if (colhalf) {
                        v += e0 * we0[ni] + e1 * we1[ni];
                        v = fmaxf(v, 0.f);
                    }
                    axyhid[(size_t)row * 512 + colhalf * 256 + c] = v;
                }
            }
    }
}

// ---------------------------------------------------------------------------
// Deep-pipelined bf16 MFMA GEMM, 4-wave 128x128 (R11/R16/R17-verified)
// ---------------------------------------------------------------------------
template<bool OUTBF16>
__global__ __launch_bounds__(256)
void gemm_dp(const float* __restrict__ A, const __bf16* __restrict__ Wt,
             const float* __restrict__ bias, void* __restrict__ outp,
             int M, int N, int LDA)
{
    __shared__ float4 AsbV[2][512];
    __shared__ float4 BsbV[3][512];
    char* const Asb_b = (char*)AsbV;
    char* const Bsb_b = (char*)BsbV;

    const int tid  = threadIdx.x;
    const int wave = tid >> 6, lane = tid & 63;
    const int wr = wave >> 1, wc = wave & 1;
    const int row0 = blockIdx.y * 128, col0 = blockIdx.x * 128;
    const int l15 = lane & 15, l4 = lane >> 4;

    const int st_row = tid >> 1, st_kh = tid & 1;
    const int gr_cl  = min(row0 + st_row, M - 1);
    const float* Abase = A + (size_t)gr_cl * LDA + st_kh * 16;
    const int asw   = (st_row >> 1) & 3;
    const int a_wo0 = st_row * 64 + ((st_kh * 2)     ^ asw) * 16;
    const int a_wo1 = st_row * 64 + ((st_kh * 2 + 1) ^ asw) * 16;

    int a_off[4], b_off[4];
    #pragma unroll
    for (int mi = 0; mi < 4; ++mi) {
        const int r   = wr * 64 + mi * 16 + l15;
        a_off[mi] = r * 64 + (l4 ^ ((r >> 1) & 3)) * 16;
    }
    #pragma unroll
    for (int ni = 0; ni < 4; ++ni) {
        const int c   = wc * 64 + ni * 16 + l15;
        b_off[ni] = c * 64 + (l4 ^ ((c >> 1) & 3)) * 16;
    }

    const __bf16* bsrc[2];
    #pragma unroll
    for (int i = 0; i < 2; ++i) {
        const int c   = (wave * 2 + i) * 64 + lane;
        const int col = c >> 2, kcp = c & 3;
        const int kc  = kcp ^ ((col >> 1) & 3);
        bsrc[i] = Wt + (size_t)(col0 + col) * 256 + kc * 8;
    }

    auto issueB = [&](int kt, int bbuf) {
        #pragma unroll
        for (int i = 0; i < 2; ++i)
            load_lds16(bsrc[i] + kt * 32, Bsb_b + bbuf * 8192 + (wave * 2 + i) * 1024);
    };
    auto loadA = [&](int kt, float4* g) {
        const float* ga = Abase + kt * 32;
        g[0] = ((const float4*)ga)[0];
        g[1] = ((const float4*)ga)[1];
        g[2] = ((const float4*)ga)[2];
        g[3] = ((const float4*)ga)[3];
    };
    auto writeA = [&](int abuf, const float4* g) {
        bf16x8 c0, c1;
        c0[0] = (__bf16)g[0].x; c0[1] = (__bf16)g[0].y; c0[2] = (__bf16)g[0].z; c0[3] = (__bf16)g[0].w;
        c0[4] = (__bf16)g[1].x; c0[5] = (__bf16)g[1].y; c0[6] = (__bf16)g[1].z; c0[7] = (__bf16)g[1].w;
        c1[0] = (__bf16)g[2].x; c1[1] = (__bf16)g[2].y; c1[2] = (__bf16)g[2].z; c1[3] = (__bf16)g[2].w;
        c1[4] = (__bf16)g[3].x; c1[5] = (__bf16)g[3].y; c1[6] = (__bf16)g[3].z; c1[7] = (__bf16)g[3].w;
        *(bf16x8*)(Asb_b + abuf * 8192 + a_wo0) = c0;
        *(bf16x8*)(Asb_b + abuf * 8192 + a_wo1) = c1;
    };

    f32x4 acc[4][4] = {};
    float4 g[2][4];

    issueB(0, 0);
    loadA(0, g[0]);
    issueB(1, 1);
    loadA(1, g[1]);
    writeA(0, g[0]);
    WAITLGKM0; BAR; CFENCE; SCHEDB;

    #pragma unroll
    for (int u = 0; u < 8; ++u) {
        if (u + 2 <= 7) {
            loadA(u + 2, g[u & 1]);
            issueB(u + 2, (u + 2) % 3);
        }

        if (u < 6)       { asm volatile("s_waitcnt vmcnt(12)" ::: "memory"); }
        else if (u == 6) { asm volatile("s_waitcnt vmcnt(6)" ::: "memory"); }
        else             { asm volatile("s_waitcnt vmcnt(0)" ::: "memory"); }
        SCHEDB;

        const char* Ab = Asb_b + (u & 1) * 8192;
        const char* Bb = Bsb_b + (u % 3) * 8192;
        bf16x8 a[4], b[4];
        #pragma unroll
        for (int mi = 0; mi < 4; ++mi) a[mi] = *(const bf16x8*)(Ab + a_off[mi]);
        #pragma unroll
        for (int ni = 0; ni < 4; ++ni) b[ni] = *(const bf16x8*)(Bb + b_off[ni]);

        #pragma unroll
        for (int mi = 0; mi < 4; ++mi)
            #pragma unroll
            for (int ni = 0; ni < 4; ++ni)
                acc[mi][ni] = __builtin_amdgcn_mfma_f32_16x16x32_bf16(
                    a[mi], b[ni], acc[mi][ni], 0, 0, 0);

        if (u + 1 <= 7) {
            writeA((u + 1) & 1, g[(u + 1) & 1]);
            WAITLGKM0; BAR; CFENCE; SCHEDB;
        }
    }

    float bb[4];
    #pragma unroll
    for (int ni = 0; ni < 4; ++ni) bb[ni] = bias[col0 + wc * 64 + ni * 16 + l15];
    #pragma unroll
    for (int mi = 0; mi < 4; ++mi) {
        #pragma unroll
        for (int rr = 0; rr < 4; ++rr) {
            const int row = row0 + wr * 64 + mi * 16 + l4 * 4 + rr;
            if (row >= M) continue;
            #pragma unroll
            for (int ni = 0; ni < 4; ++ni) {
                const float v = acc[mi][ni][rr] + bb[ni];
                const int colb = col0 + wc * 64 + ni * 16 + l15;
                if (OUTBF16) ((__bf16*)outp)[(size_t)row * N + colb] = (__bf16)v;
                else         ((float*)outp)[(size_t)row * N + colb]  = v;
            }
        }
    }
}

// ---------------------------------------------------------------------------
// Fused: softmax (spec cancels) + locations + VECTORIZED bilinear sampling.
// XCD-aware bq swizzle (T1, R17-verified): bq = (bid&7)*900 + (bid>>3).
// ---------------------------------------------------------------------------
__global__ __launch_bounds__(256)
void attn_sample_kernel(const float* __restrict__ axyhid,
                        const float* __restrict__ refp, const float* __restrict__ objs,
                        const float* __restrict__ off, const __bf16* __restrict__ v,
                        float* __restrict__ agg)
{
    const int bid = blockIdx.x;
    const int bq  = (bid & 7) * 900 + (bid >> 3);
    const int b   = bid & 7;
    const int tid = threadIdx.x;

    __shared__ float sm[128];
    __shared__ float sa[128];
    __shared__ float sl[256];

    if (tid < 128)
        sm[tid] = axyhid[(size_t)bq * 512 + tid] * axyhid[(size_t)bq * 512 + 128 + tid];
    __syncthreads();

    if (tid < 128) {
        const int hh = tid >> 4;
        float mx = -1e30f;
        #pragma unroll
        for (int i = 0; i < 16; ++i) mx = fmaxf(mx, sm[hh * 16 + i]);
        float s = 0.f;
        #pragma unroll
        for (int i = 0; i < 16; ++i) s += __expf(sm[hh * 16 + i] - mx);
        sa[tid] = __expf(sm[tid] - mx) / s;

        const int l = (tid >> 2) & 3;
        const float os0 = objs[(size_t)bq * 2], os1 = objs[(size_t)bq * 2 + 1];
        const float r0 = refp[((size_t)bq * 4 + l) * 2];
        const float r1 = refp[((size_t)bq * 4 + l) * 2 + 1];
        const float o0 = off[(size_t)bq * 256 + tid * 2]     * os0;
        const float o1 = off[(size_t)bq * 256 + tid * 2 + 1] * os1;
        sl[tid * 2]     = fminf(fmaxf(r0 + o0, 0.f), 1.f);
        sl[tid * 2 + 1] = fminf(fmaxf(r1 + o1, 0.f), 1.f);
    }
    __syncthreads();

    const int h = tid >> 5, lane32 = tid & 31;
    const int sp = lane32 >> 2, cq = lane32 & 3;
    const int chbase = h * 32 + cq * 8;
    const __bf16* vb = v + (size_t)b * S_ * 256;

    float acc8[8] = {};

    #pragma unroll
    for (int gidx = 0; gidx < 2; ++gidx) {
        const int lp  = gidx * 8 + sp;
        const int li  = h * 16 + lp;
        const int lvl = lp >> 2;
        const int Wl = (lvl == 0) ? 100 : (lvl == 1) ? 50 : (lvl == 2) ? 25 : 13;
        const int Hl = Wl;
        const int st = (lvl == 0) ? 0 : (lvl == 1) ? 10000 : (lvl == 2) ? 12500 : 13125;

        const float a  = sa[li];
        const float lx = sl[li * 2], ly = sl[li * 2 + 1];
        const float x = lx * (float)Wl - 0.5f;
        const float y = ly * (float)Hl - 0.5f;
        const float x0f = floorf(x), y0f = floorf(y);
        const float fx = x - x0f, fy = y - y0f;
        const int x0 = (int)x0f, y0 = (int)y0f;

        #pragma unroll
        for (int c = 0; c < 4; ++c) {
            const int dx = c & 1, dy = c >> 1;
            const int xi = x0 + dx, yi = y0 + dy;
            const float wgt = (dx ? fx : 1.f - fx) * (dy ? fy : 1.f - fy);
            const bool valid = (xi >= 0) & (xi < Wl) & (yi >= 0) & (yi < Hl);
            const int idx = min(max(yi, 0), Hl - 1) * Wl + min(max(xi, 0), Wl - 1);
            const float wa = valid ? a * wgt : 0.f;
            const bf16x8 gv = *(const bf16x8*)(vb + (size_t)(st + idx) * 256 + chbase);
            #pragma unroll
            for (int j = 0; j < 8; ++j) acc8[j] += wa * (float)gv[j];
        }
    }

    #pragma unroll
    for (int m = 4; m <= 16; m <<= 1)
        #pragma unroll
        for (int j = 0; j < 8; ++j)
            acc8[j] += __shfl_xor(acc8[j], m);

    if (sp == 0) {
        #pragma unroll
        for (int j = 0; j < 8; ++j)
            agg[(size_t)bq * 256 + chbase + j] = acc8[j];
    }
}

// ---------------------------------------------------------------------------
extern "C" void kernel_launch(void* const* d_in, const int* in_sizes, int n_in,
                              void* d_out, int out_size, void* d_ws, size_t ws_size,
                              hipStream_t stream)
{
    const float* query = (const float*)d_in[0];
    const float* refp  = (const float*)d_in[1];
    const float* x_in  = (const float*)d_in[2];
    const float* objs  = (const float*)d_in[3];
    const float* w_q    = (const float*)d_in[6];
    const float* b_q    = (const float*)d_in[7];
    const float* w_v    = (const float*)d_in[8];
    const float* b_v    = (const float*)d_in[9];
    const float* w_o    = (const float*)d_in[10];
    const float* b_o    = (const float*)d_in[11];
    const float* w_off1 = (const float*)d_in[12];
    const float* b_off1 = (const float*)d_in[13];
    const float* w_off2 = (const float*)d_in[14];
    const float* b_off2 = (const float*)d_in[15];
    const float* w_ax   = (const float*)d_in[16];
    const float* b_ax   = (const float*)d_in[17];
    const float* w_ay   = (const float*)d_in[18];
    const float* b_ay   = (const float*)d_in[19];

    float* ws = (float*)d_ws;
    float* axyhid_ws = ws;                               // BQ*512 f32
    float* off_ws    = axyhid_ws + (size_t)BQ * 512;     // BQ*256 f32
    float* agg_ws    = off_ws    + (size_t)BQ * 256;     // BQ*256 f32
    float* bcomb_ws  = agg_ws    + (size_t)BQ * 256;     // 512 f32
    __bf16* v_bf    = (__bf16*)(bcomb_ws + 512);         // BS*256 bf16
    __bf16* wt_v    = v_bf    + (size_t)BS * 256;
    __bf16* wt_o    = wt_v    + 256 * 256;
    __bf16* wt_off2 = wt_o    + 256 * 256;
    __bf16* wt_cat  = wt_off2 + 256 * 256;               // 512*256
    __bf16* wcomb   = wt_cat  + 512 * 256;               // 512*256

    const dim3 blk(256);

    // weight prep (R11-verified split form)
    transpose_all<<<320, blk, 0, stream>>>(w_v, w_o, w_off1, w_off2, w_ax, w_ay,
                                           wt_v, wt_o, wt_off2, wt_cat);
    combine2<<<10, blk, 0, stream>>>(wt_cat, w_q, b_q, b_ax, b_ay, b_off1,
                                     wcomb, bcomb_ws);

    // fused: v-GEMM (831 blocks) + axyhid GEMM (114 blocks)
    main_fused<<<NVB + 114, dim3(512), 0, stream>>>(
        x_in, wt_v, b_v, v_bf,
        query, wcomb, bcomb_ws, objs, w_off1 + 256 * 256, axyhid_ws);

    // offsets = hid @ w_off2 + b_off2 -> f32
    gemm_dp<false><<<dim3(2, (BQ + 127) / 128), blk, 0, stream>>>(
        axyhid_ws + 256, wt_off2, b_off2, off_ws, BQ, 256, 512);

    // fused softmax/locs/sampling (vectorized gathers + XCD swizzle)
    attn_sample_kernel<<<BQ, blk, 0, stream>>>(axyhid_ws, refp, objs, off_ws,
                                               v_bf, agg_ws);

    // out = agg @ w_o + b_o -> f32
    gemm_dp<false><<<dim3(2, (BQ + 127) / 128), blk, 0, stream>>>(
        agg_ws, wt_o, b_o, (float*)d_out, BQ, 256, 256);
}